// Round 1
// baseline (225.102 us; speedup 1.0000x reference)
//
#include <hip/hip_runtime.h>
#include <hip/hip_bf16.h>

typedef __hip_bfloat16 bf16;
typedef __attribute__((ext_vector_type(8))) short bf16x8;   // 8 bf16 = 4 VGPRs (MFMA A/B frag)
typedef __attribute__((ext_vector_type(4))) float f32x4;    // MFMA C/D frag

#define MFMA(a, b, c) __builtin_amdgcn_mfma_f32_16x16x32_bf16((a), (b), (c), 0, 0, 0)

static __device__ __forceinline__ float bf2f(bf16 b) { return __bfloat162float(b); }

// ---------------------------------------------------------------------------
// Phase 0a: convert hidden_states (4096x1024) and dist_emb (4095x64) to bf16
// ---------------------------------------------------------------------------
__global__ void prep_convert(const float* __restrict__ X, const float* __restrict__ DE,
                             bf16* __restrict__ Xb, bf16* __restrict__ DEb) {
    int i = blockIdx.x * blockDim.x + threadIdx.x;
    if (i < 1048576) {                       // 4194304 / 4 float4's of X
        float4 v = reinterpret_cast<const float4*>(X)[i];
        bf16* d = Xb + 4 * i;
        d[0] = __float2bfloat16(v.x); d[1] = __float2bfloat16(v.y);
        d[2] = __float2bfloat16(v.z); d[3] = __float2bfloat16(v.w);
    } else {
        int j = i - 1048576;
        if (j < 65520) {                     // 262080 / 4 float4's of dist_emb
            float4 v = reinterpret_cast<const float4*>(DE)[j];
            bf16* d = DEb + 4 * j;
            d[0] = __float2bfloat16(v.x); d[1] = __float2bfloat16(v.y);
            d[2] = __float2bfloat16(v.z); d[3] = __float2bfloat16(v.w);
        }
    }
}

// ---------------------------------------------------------------------------
// Phase 0b: transpose Wq/Wk/Wv (1024x1024 f32, [in][out]) -> WT bf16 [out][in]
// ---------------------------------------------------------------------------
__global__ void prep_transpose_w(const float* __restrict__ Wq, const float* __restrict__ Wk,
                                 const float* __restrict__ Wv, bf16* __restrict__ WTb) {
    const float* W = (blockIdx.z == 0) ? Wq : (blockIdx.z == 1) ? Wk : Wv;
    bf16* WT = WTb + (size_t)blockIdx.z * (1024u * 1024u);
    __shared__ float t[64][65];
    int tid = threadIdx.x;
    int col = tid & 63;
    int r4 = tid >> 6;
    int i0 = blockIdx.x * 64, o0 = blockIdx.y * 64;
    for (int it = 0; it < 16; ++it) {
        int row = it * 4 + r4;
        t[row][col] = W[(size_t)(i0 + row) * 1024 + o0 + col];   // coalesced read
    }
    __syncthreads();
    for (int it = 0; it < 16; ++it) {
        int row = it * 4 + r4;
        WT[(size_t)(o0 + row) * 1024 + i0 + col] = __float2bfloat16(t[col][row]);
    }
}

// ---------------------------------------------------------------------------
// Phase 1: QKV projection GEMM. C[4096x1024] = Xb * W (+bias), per-head layout out.
//   Q,K -> [B,H,S,64] bf16 ; V -> transposed [B,H,64,S] bf16 (for PV B-operand).
// 128x128 tile, BK=64, 4 waves (2x2), each wave 64x64 (4x4 frags of 16x16x32).
// ---------------------------------------------------------------------------
__global__ __launch_bounds__(256, 2) void proj_gemm(
    const bf16* __restrict__ Xb, const bf16* __restrict__ WTb,
    const float* __restrict__ bq, const float* __restrict__ bk, const float* __restrict__ bv,
    bf16* __restrict__ Qb, bf16* __restrict__ Kb, bf16* __restrict__ VTb) {
    int proj = blockIdx.z;
    const bf16* W = WTb + (size_t)proj * (1024u * 1024u);
    const float* bias = (proj == 0) ? bq : (proj == 1) ? bk : bv;

    __shared__ bf16 XT[128][72];
    __shared__ bf16 WTt[128][72];

    int tid = threadIdx.x;
    int w = tid >> 6, lane = tid & 63, g = lane >> 4, li = lane & 15;
    int wr = w >> 1, wc = w & 1;
    int m0 = blockIdx.x * 128, n0 = blockIdx.y * 128;

    f32x4 acc[4][4];
    for (int mt = 0; mt < 4; mt++)
        for (int nt = 0; nt < 4; nt++) acc[mt][nt] = {0.f, 0.f, 0.f, 0.f};

    for (int ks = 0; ks < 16; ++ks) {
        for (int it = 0; it < 4; ++it) {        // stage 128x64 bf16 tiles (16B/thread chunks)
            int idx = tid + 256 * it;
            int row = idx >> 3, c = (idx & 7) * 8;
            *reinterpret_cast<bf16x8*>(&XT[row][c]) =
                *reinterpret_cast<const bf16x8*>(Xb + (size_t)(m0 + row) * 1024 + ks * 64 + c);
            *reinterpret_cast<bf16x8*>(&WTt[row][c]) =
                *reinterpret_cast<const bf16x8*>(W + (size_t)(n0 + row) * 1024 + ks * 64 + c);
        }
        __syncthreads();
        for (int kk = 0; kk < 2; ++kk) {
            bf16x8 af[4], bfr[4];
            for (int mt = 0; mt < 4; mt++)
                af[mt] = *reinterpret_cast<const bf16x8*>(&XT[64 * wr + 16 * mt + li][32 * kk + 8 * g]);
            for (int nt = 0; nt < 4; nt++)
                bfr[nt] = *reinterpret_cast<const bf16x8*>(&WTt[64 * wc + 16 * nt + li][32 * kk + 8 * g]);
            for (int mt = 0; mt < 4; mt++)
                for (int nt = 0; nt < 4; nt++)
                    acc[mt][nt] = MFMA(af[mt], bfr[nt], acc[mt][nt]);
        }
        __syncthreads();
    }

    // Epilogue: +bias, convert, scatter to per-head layouts.
    // D-frag: col n-local = 16*nt + li ; row m-local = 4*g + r
    for (int mt = 0; mt < 4; mt++)
        for (int nt = 0; nt < 4; nt++) {
            int n = n0 + 64 * wc + 16 * nt + li;
            int h = n >> 6, d = n & 63;
            float bv_ = bias[n];
            for (int r = 0; r < 4; r++) {
                int m = m0 + 64 * wr + 16 * mt + 4 * g + r;
                int b = m >> 10, s = m & 1023;
                bf16 o = __float2bfloat16(acc[mt][nt][r] + bv_);
                if (proj == 0)      Qb[((size_t)(b * 16 + h) * 1024 + s) * 64 + d] = o;
                else if (proj == 1) Kb[((size_t)(b * 16 + h) * 1024 + s) * 64 + d] = o;
                else                VTb[((size_t)(b * 16 + h) * 64 + d) * 1024 + s] = o;
            }
        }
}

// ---------------------------------------------------------------------------
// Phase 2: fused attention with relative_key_query bias, flash-style.
// Block = 4 waves, Q-tile 64 rows (wave w owns rows 16w..16w+15), K-tile 64.
// Per K-step: S = Q*K^T ; QD = Q*DE^T, KD = K*DE^T (DE = 127 distance rows);
// bias gather from LDS; online softmax; PV via transposed V.
// ---------------------------------------------------------------------------
__global__ __launch_bounds__(256, 2) void attn_fused(
    const bf16* __restrict__ Qb, const bf16* __restrict__ Kb,
    const bf16* __restrict__ VTb, const bf16* __restrict__ DEb,
    const float* __restrict__ mask, float* __restrict__ out) {
    const int S = 1024, D = 64;
    int blk = blockIdx.x;
    int qb = blk & 15;          // Q block within (b,h)
    int bh = blk >> 4;          // b*16 + h
    int b = bh >> 4, h = bh & 15;
    int L0 = qb * 64;

    int tid = threadIdx.x;
    int w = tid >> 6;
    int lane = tid & 63;
    int g = lane >> 4, li = lane & 15;

    __shared__ bf16 K_lds[64][72];     // K rows [r0..r0+64) x 64
    __shared__ bf16 VT_lds[64][72];    // V^T: [d][r-local]
    __shared__ bf16 DE_lds[128][72];   // distance rows dmin..dmin+127
    __shared__ bf16 QD_lds[64][132];   // QD[l-local][j]
    __shared__ bf16 KD_lds[64][132];   // KD[r-local][j]
    __shared__ bf16 P_lds[4][16][72];  // per-wave P transpose buffer

    const bf16* Qh = Qb + (size_t)bh * S * D;
    const bf16* Kh = Kb + (size_t)bh * S * D;
    const bf16* Vh = VTb + (size_t)bh * D * S;
    const float* maskb = mask + b * S;

    // Q a-frags (row = li within wave's 16 rows, k = 32*kk + 8*g + j), kept in regs
    bf16x8 qa0, qa1;
    {
        const bf16* qrow = Qh + (size_t)(L0 + 16 * w + li) * D;
        qa0 = *reinterpret_cast<const bf16x8*>(qrow + 8 * g);
        qa1 = *reinterpret_cast<const bf16x8*>(qrow + 32 + 8 * g);
    }

    f32x4 acc_o[4];
    for (int dt = 0; dt < 4; dt++) acc_o[dt] = {0.f, 0.f, 0.f, 0.f};
    float m_run[4], l_run[4];
    for (int r = 0; r < 4; r++) { m_run[r] = -1e30f; l_run[r] = 0.f; }

    for (int kt = 0; kt < 16; ++kt) {
        int r0 = kt * 64;
        // ---- stage K tile, VT tile ----
        for (int it = 0; it < 2; ++it) {
            int idx = tid + it * 256;
            int row = idx >> 3, c = (idx & 7) * 8;
            *reinterpret_cast<bf16x8*>(&K_lds[row][c]) =
                *reinterpret_cast<const bf16x8*>(Kh + (size_t)(r0 + row) * D + c);
            *reinterpret_cast<bf16x8*>(&VT_lds[row][c]) =
                *reinterpret_cast<const bf16x8*>(Vh + (size_t)row * S + r0 + c);
        }
        // ---- stage DE tile: distance j=0..127 <-> global row de0+j ----
        int de0 = L0 - r0 + 1984;  // (L0 - r0 - 63) + 2047 ; always in [1024, 2944]
        for (int it = 0; it < 4; ++it) {
            int idx = tid + it * 256;
            int row = idx >> 3, c = (idx & 7) * 8;
            *reinterpret_cast<bf16x8*>(&DE_lds[row][c]) =
                *reinterpret_cast<const bf16x8*>(DEb + (size_t)(de0 + row) * 64 + c);
        }
        __syncthreads();

        // ---- QK^T frags: D[m=q-row-local][n=16*nt+li] ----
        f32x4 s_acc[4];
        for (int nt = 0; nt < 4; ++nt) {
            bf16x8 kb0 = *reinterpret_cast<const bf16x8*>(&K_lds[16 * nt + li][8 * g]);
            bf16x8 kb1 = *reinterpret_cast<const bf16x8*>(&K_lds[16 * nt + li][32 + 8 * g]);
            f32x4 a = {0.f, 0.f, 0.f, 0.f};
            a = MFMA(qa0, kb0, a);
            a = MFMA(qa1, kb1, a);
            s_acc[nt] = a;
        }

        // ---- QD & KD via MFMA, write bf16 to LDS ----
        bf16x8 ka0 = *reinterpret_cast<const bf16x8*>(&K_lds[16 * w + li][8 * g]);
        bf16x8 ka1 = *reinterpret_cast<const bf16x8*>(&K_lds[16 * w + li][32 + 8 * g]);
        for (int jt = 0; jt < 8; ++jt) {
            bf16x8 de0v = *reinterpret_cast<const bf16x8*>(&DE_lds[16 * jt + li][8 * g]);
            bf16x8 de1v = *reinterpret_cast<const bf16x8*>(&DE_lds[16 * jt + li][32 + 8 * g]);
            f32x4 aq = {0.f, 0.f, 0.f, 0.f};
            aq = MFMA(qa0, de0v, aq);
            aq = MFMA(qa1, de1v, aq);
            f32x4 ak = {0.f, 0.f, 0.f, 0.f};
            ak = MFMA(ka0, de0v, ak);
            ak = MFMA(ka1, de1v, ak);
            for (int r = 0; r < 4; r++) {
                QD_lds[16 * w + 4 * g + r][16 * jt + li] = __float2bfloat16(aq[r]);
                KD_lds[16 * w + 4 * g + r][16 * jt + li] = __float2bfloat16(ak[r]);
            }
        }
        __syncthreads();   // KD is consumed cross-wave

        // ---- assemble scores + online softmax ----
        float p[4][4];
        float tmax[4] = {-1e30f, -1e30f, -1e30f, -1e30f};
        for (int nt = 0; nt < 4; ++nt) {
            int rloc = 16 * nt + li;
            float mk = maskb[r0 + rloc];
            for (int r = 0; r < 4; r++) {
                int lloc = 16 * w + 4 * g + r;
                int js = lloc - rloc + 63;   // in [0,126]
                float bias = bf2f(QD_lds[lloc][js]) + bf2f(KD_lds[rloc][js]);
                float sv = (s_acc[nt][r] + bias) * 0.125f + mk;
                p[nt][r] = sv;
                tmax[r] = fmaxf(tmax[r], sv);
            }
        }
        for (int r = 0; r < 4; r++) {
            float t = tmax[r];
            t = fmaxf(t, __shfl_xor(t, 1, 16));
            t = fmaxf(t, __shfl_xor(t, 2, 16));
            t = fmaxf(t, __shfl_xor(t, 4, 16));
            t = fmaxf(t, __shfl_xor(t, 8, 16));
            float mnew = fmaxf(m_run[r], t);
            float scl = exp2f((m_run[r] - mnew) * 1.44269504f);
            m_run[r] = mnew;
            float s = 0.f;
            for (int nt = 0; nt < 4; nt++) {
                float pv = exp2f((p[nt][r] - mnew) * 1.44269504f);
                p[nt][r] = pv;
                s += pv;
            }
            s += __shfl_xor(s, 1, 16);
            s += __shfl_xor(s, 2, 16);
            s += __shfl_xor(s, 4, 16);
            s += __shfl_xor(s, 8, 16);
            l_run[r] = l_run[r] * scl + s;
            for (int dt = 0; dt < 4; dt++) acc_o[dt][r] *= scl;
        }

        // ---- P (D-layout) -> wave-private LDS -> A-frags; PV MFMA ----
        for (int nt = 0; nt < 4; nt++)
            for (int r = 0; r < 4; r++)
                P_lds[w][4 * g + r][16 * nt + li] = __float2bfloat16(p[nt][r]);
        // same-wave DS ordering: reads below depend through LDS, compiler orders them
        bf16x8 pa0 = *reinterpret_cast<const bf16x8*>(&P_lds[w][li][8 * g]);
        bf16x8 pa1 = *reinterpret_cast<const bf16x8*>(&P_lds[w][li][32 + 8 * g]);
        for (int dt = 0; dt < 4; dt++) {
            bf16x8 vb0 = *reinterpret_cast<const bf16x8*>(&VT_lds[16 * dt + li][8 * g]);
            bf16x8 vb1 = *reinterpret_cast<const bf16x8*>(&VT_lds[16 * dt + li][32 + 8 * g]);
            acc_o[dt] = MFMA(pa0, vb0, acc_o[dt]);
            acc_o[dt] = MFMA(pa1, vb1, acc_o[dt]);
        }
        __syncthreads();   // protect tiles before next iteration's staging
    }

    // ---- epilogue: out[b][s][h*64+d], s = L0+16w+4g+r, d = 16*dt+li ----
    for (int dt = 0; dt < 4; dt++)
        for (int r = 0; r < 4; r++) {
            int srow = L0 + 16 * w + 4 * g + r;
            out[((size_t)b * 1024 + srow) * 1024 + (size_t)h * 64 + 16 * dt + li] =
                acc_o[dt][r] / l_run[r];
        }
}

// ---------------------------------------------------------------------------
extern "C" void kernel_launch(void* const* d_in, const int* in_sizes, int n_in,
                              void* d_out, int out_size, void* d_ws, size_t ws_size,
                              hipStream_t stream) {
    const float* X   = (const float*)d_in[0];
    const float* msk = (const float*)d_in[1];
    const float* Wq  = (const float*)d_in[2];
    const float* bq  = (const float*)d_in[3];
    const float* Wk  = (const float*)d_in[4];
    const float* bk  = (const float*)d_in[5];
    const float* Wv  = (const float*)d_in[6];
    const float* bv  = (const float*)d_in[7];
    const float* DE  = (const float*)d_in[8];
    float* out = (float*)d_out;

    // workspace layout (bf16 elements): ~38.5 MB total
    bf16* ws  = (bf16*)d_ws;
    bf16* Xb  = ws;              // 4194304  : X as bf16 [4096][1024]
    bf16* WTb = ws + 4194304;    // 3145728  : Wq/Wk/Wv transposed bf16 [out][in]
    bf16* DEb = ws + 7340032;    // 262144   : dist_emb bf16 [4095][64] (padded)
    bf16* Qb  = ws + 7602176;    // 4194304  : Q [B,H,S,64]
    bf16* Kb  = ws + 11796480;   // 4194304  : K [B,H,S,64]
    bf16* VTb = ws + 15990784;   // 4194304  : V^T [B,H,64,S]

    prep_convert<<<4352, 256, 0, stream>>>(X, DE, Xb, DEb);
    prep_transpose_w<<<dim3(16, 16, 3), 256, 0, stream>>>(Wq, Wk, Wv, WTb);
    proj_gemm<<<dim3(32, 8, 3), 256, 0, stream>>>(Xb, WTb, bq, bk, bv, Qb, Kb, VTb);
    attn_fused<<<dim3(1024), 256, 0, stream>>>(Qb, Kb, VTb, DEb, msk, out);
}

// Round 2
// 155.954 us; speedup vs baseline: 1.4434x; 1.4434x over previous
//
#include <hip/hip_runtime.h>
#include <hip/hip_bf16.h>

typedef __hip_bfloat16 bf16;
typedef __attribute__((ext_vector_type(8))) short bf16x8;   // 8 bf16 = 4 VGPRs (MFMA A/B frag)
typedef __attribute__((ext_vector_type(4))) float f32x4;    // MFMA C/D frag

#define MFMA(a, b, c) __builtin_amdgcn_mfma_f32_16x16x32_bf16((a), (b), (c), 0, 0, 0)
#define DPPF(x, ctrl) __builtin_bit_cast(float, __builtin_amdgcn_update_dpp(0, __builtin_bit_cast(int, (x)), (ctrl), 0xF, 0xF, true))

static __device__ __forceinline__ float red16max(float x) {
    x = fmaxf(x, DPPF(x, 0xB1));    // quad_perm xor1
    x = fmaxf(x, DPPF(x, 0x4E));    // quad_perm xor2
    x = fmaxf(x, DPPF(x, 0x124));   // row_ror:4
    x = fmaxf(x, DPPF(x, 0x128));   // row_ror:8
    return x;
}
static __device__ __forceinline__ float red16sum(float x) {
    x += DPPF(x, 0xB1);
    x += DPPF(x, 0x4E);
    x += DPPF(x, 0x124);
    x += DPPF(x, 0x128);
    return x;
}
static __device__ __forceinline__ unsigned short f2bu(float x) {
    __hip_bfloat16 h = __float2bfloat16(x);
    return *reinterpret_cast<unsigned short*>(&h);
}

// ---------------------------------------------------------------------------
// Phase 0a: convert hidden_states (4096x1024) and dist_emb (4095x64) to bf16
// ---------------------------------------------------------------------------
__global__ void prep_convert(const float* __restrict__ X, const float* __restrict__ DE,
                             bf16* __restrict__ Xb, bf16* __restrict__ DEb) {
    int i = blockIdx.x * blockDim.x + threadIdx.x;
    if (i < 1048576) {
        float4 v = reinterpret_cast<const float4*>(X)[i];
        bf16* d = Xb + 4 * i;
        d[0] = __float2bfloat16(v.x); d[1] = __float2bfloat16(v.y);
        d[2] = __float2bfloat16(v.z); d[3] = __float2bfloat16(v.w);
    } else {
        int j = i - 1048576;
        if (j < 65520) {
            float4 v = reinterpret_cast<const float4*>(DE)[j];
            bf16* d = DEb + 4 * j;
            d[0] = __float2bfloat16(v.x); d[1] = __float2bfloat16(v.y);
            d[2] = __float2bfloat16(v.z); d[3] = __float2bfloat16(v.w);
        }
    }
}

// ---------------------------------------------------------------------------
// Phase 0b: transpose Wq/Wk/Wv (1024x1024 f32, [in][out]) -> WT bf16 [out][in]
// ---------------------------------------------------------------------------
__global__ void prep_transpose_w(const float* __restrict__ Wq, const float* __restrict__ Wk,
                                 const float* __restrict__ Wv, bf16* __restrict__ WTb) {
    const float* W = (blockIdx.z == 0) ? Wq : (blockIdx.z == 1) ? Wk : Wv;
    bf16* WT = WTb + (size_t)blockIdx.z * (1024u * 1024u);
    __shared__ float t[64][65];
    int tid = threadIdx.x;
    int col = tid & 63;
    int r4 = tid >> 6;
    int i0 = blockIdx.x * 64, o0 = blockIdx.y * 64;
    for (int it = 0; it < 16; ++it) {
        int row = it * 4 + r4;
        t[row][col] = W[(size_t)(i0 + row) * 1024 + o0 + col];
    }
    __syncthreads();
    for (int it = 0; it < 16; ++it) {
        int row = it * 4 + r4;
        WT[(size_t)(o0 + row) * 1024 + i0 + col] = __float2bfloat16(t[col][row]);
    }
}

// ---------------------------------------------------------------------------
// Phase 1: QKV projection GEMM (unchanged from r1 — passed).
// ---------------------------------------------------------------------------
__global__ __launch_bounds__(256, 2) void proj_gemm(
    const bf16* __restrict__ Xb, const bf16* __restrict__ WTb,
    const float* __restrict__ bq, const float* __restrict__ bk, const float* __restrict__ bv,
    bf16* __restrict__ Qb, bf16* __restrict__ Kb, bf16* __restrict__ VTb) {
    int proj = blockIdx.z;
    const bf16* W = WTb + (size_t)proj * (1024u * 1024u);
    const float* bias = (proj == 0) ? bq : (proj == 1) ? bk : bv;

    __shared__ bf16 XT[128][72];
    __shared__ bf16 WTt[128][72];

    int tid = threadIdx.x;
    int w = tid >> 6, lane = tid & 63, g = lane >> 4, li = lane & 15;
    int wr = w >> 1, wc = w & 1;
    int m0 = blockIdx.x * 128, n0 = blockIdx.y * 128;

    f32x4 acc[4][4];
    for (int mt = 0; mt < 4; mt++)
        for (int nt = 0; nt < 4; nt++) acc[mt][nt] = {0.f, 0.f, 0.f, 0.f};

    for (int ks = 0; ks < 16; ++ks) {
        for (int it = 0; it < 4; ++it) {
            int idx = tid + 256 * it;
            int row = idx >> 3, c = (idx & 7) * 8;
            *reinterpret_cast<bf16x8*>(&XT[row][c]) =
                *reinterpret_cast<const bf16x8*>(Xb + (size_t)(m0 + row) * 1024 + ks * 64 + c);
            *reinterpret_cast<bf16x8*>(&WTt[row][c]) =
                *reinterpret_cast<const bf16x8*>(W + (size_t)(n0 + row) * 1024 + ks * 64 + c);
        }
        __syncthreads();
        for (int kk = 0; kk < 2; ++kk) {
            bf16x8 af[4], bfr[4];
            for (int mt = 0; mt < 4; mt++)
                af[mt] = *reinterpret_cast<const bf16x8*>(&XT[64 * wr + 16 * mt + li][32 * kk + 8 * g]);
            for (int nt = 0; nt < 4; nt++)
                bfr[nt] = *reinterpret_cast<const bf16x8*>(&WTt[64 * wc + 16 * nt + li][32 * kk + 8 * g]);
            for (int mt = 0; mt < 4; mt++)
                for (int nt = 0; nt < 4; nt++)
                    acc[mt][nt] = MFMA(af[mt], bfr[nt], acc[mt][nt]);
        }
        __syncthreads();
    }

    for (int mt = 0; mt < 4; mt++)
        for (int nt = 0; nt < 4; nt++) {
            int n = n0 + 64 * wc + 16 * nt + li;
            int h = n >> 6, d = n & 63;
            float bv_ = bias[n];
            for (int r = 0; r < 4; r++) {
                int m = m0 + 64 * wr + 16 * mt + 4 * g + r;
                int b = m >> 10, s = m & 1023;
                bf16 o = __float2bfloat16(acc[mt][nt][r] + bv_);
                if (proj == 0)      Qb[((size_t)(b * 16 + h) * 1024 + s) * 64 + d] = o;
                else if (proj == 1) Kb[((size_t)(b * 16 + h) * 1024 + s) * 64 + d] = o;
                else                VTb[((size_t)(b * 16 + h) * 64 + d) * 1024 + s] = o;
            }
        }
}

// ---------------------------------------------------------------------------
// Phase 2: fused attention v2 — LDS-pipe-optimized.
// Wave w: QD for its 16 Q-rows AND KD for K-group (3-w); both use the SAME
// DE window [16w,16w+80) -> shared DE frags. Transposed QD/KD stores (b64),
// kt-invariant gather bases, DPP softmax reduce, 2 barriers/kt, VT dbuf,
// rolling DE window, T14 async stage, XCD swizzle.
// ---------------------------------------------------------------------------
__global__ __launch_bounds__(256, 2) void attn_fused(
    const bf16* __restrict__ Qg, const bf16* __restrict__ Kg,
    const bf16* __restrict__ VTg, const bf16* __restrict__ DEb,
    const float* __restrict__ mask, float* __restrict__ out) {
    const int S = 1024, D = 64;
    // XCD-aware remap: the 16 blocks of one (b,h) land on the same XCD.
    int p = blockIdx.x;
    int bh = (p & 7) * 8 + ((p >> 3) >> 4);
    int qb = (p >> 3) & 15;
    int b = bh >> 4;
    int L0 = qb * 64;

    int tid = threadIdx.x;
    int w = tid >> 6, lane = tid & 63, g = lane >> 4, li = lane & 15;

    __shared__ bf16 K_lds[64][72];        // 9216 B
    __shared__ bf16 VT_lds[2][64][72];    // 18432 B (double-buffered)
    __shared__ bf16 DE_lds[128][72];      // 18432 B (circular, phys = global & 127)
    __shared__ bf16 QD_T[4][80][20];      // 12800 B  [wave][col c][row 4g+r]
    __shared__ bf16 KD_T[80][68];         // 10880 B  [col c][rloc]
    __shared__ bf16 P_lds[4][16][72];     //  9216 B

    const bf16* Qh = Qg + (size_t)bh * S * D;
    const bf16* Kh = Kg + (size_t)bh * S * D;
    const bf16* Vh = VTg + (size_t)bh * D * S;
    const float* maskb = mask + b * S;

    int srow = tid >> 3;          // 0..31
    int scol = (tid & 7) * 8;     // 0..56

    // Q a-frags in registers
    bf16x8 qa0, qa1;
    {
        const bf16* qrow = Qh + (size_t)(L0 + 16 * w + li) * D;
        qa0 = *reinterpret_cast<const bf16x8*>(qrow + 8 * g);
        qa1 = *reinterpret_cast<const bf16x8*>(qrow + 32 + 8 * g);
    }

    // kt-invariant gather base pointers
    const char* qdb = (const char*)(&QD_T[w][0][0]) + (40 * (4 * g - li + 15) + 8 * g);
    const char* kdb = (const char*)(&KD_T[0][0]) + (136 * (16 * w + 4 * g - li + 15) + 2 * li);

    // Prologue: stage K(0), VT[0](0), full 128-row DE window
    int de00 = L0 + 1984;     // de0 at kt=0
    {
        for (int c = 0; c < 2; ++c) {
            int row = srow + 32 * c;
            *reinterpret_cast<bf16x8*>(&K_lds[row][scol]) =
                *reinterpret_cast<const bf16x8*>(Kh + (size_t)row * D + scol);
            *reinterpret_cast<bf16x8*>(&VT_lds[0][row][scol]) =
                *reinterpret_cast<const bf16x8*>(Vh + (size_t)row * S + scol);
        }
        for (int c = 0; c < 4; ++c) {
            int j = srow + 32 * c;
            *reinterpret_cast<bf16x8*>(&DE_lds[(de00 + j) & 127][scol]) =
                *reinterpret_cast<const bf16x8*>(DEb + (size_t)(de00 + j) * 64 + scol);
        }
    }

    f32x4 acc_o[4];
    for (int dt = 0; dt < 4; dt++) acc_o[dt] = {0.f, 0.f, 0.f, 0.f};
    float m_run[4], l_run[4];
    for (int r = 0; r < 4; r++) { m_run[r] = -1e30f; l_run[r] = 0.f; }

    __syncthreads();

    for (int kt = 0; kt < 16; ++kt) {
        int r0 = kt * 64;
        int de0 = de00 - r0;
        bool has_next = (kt < 15);

        // ---- T14: issue next-tile global loads (fly during MFMA phase) ----
        bf16x8 sK0, sK1, sV0, sV1, sD0, sD1;
        if (has_next) {
            int r0n = r0 + 64;
            int dlo = de0 - 64;
            sK0 = *reinterpret_cast<const bf16x8*>(Kh + (size_t)(r0n + srow) * D + scol);
            sK1 = *reinterpret_cast<const bf16x8*>(Kh + (size_t)(r0n + srow + 32) * D + scol);
            sV0 = *reinterpret_cast<const bf16x8*>(Vh + (size_t)srow * S + r0n + scol);
            sV1 = *reinterpret_cast<const bf16x8*>(Vh + (size_t)(srow + 32) * S + r0n + scol);
            sD0 = *reinterpret_cast<const bf16x8*>(DEb + (size_t)(dlo + srow) * 64 + scol);
            sD1 = *reinterpret_cast<const bf16x8*>(DEb + (size_t)(dlo + srow + 32) * 64 + scol);
        }

        // ---- Phase B: QK^T ----
        f32x4 s_acc[4];
        __builtin_amdgcn_s_setprio(1);
        for (int nt = 0; nt < 4; ++nt) {
            bf16x8 kb0 = *reinterpret_cast<const bf16x8*>(&K_lds[16 * nt + li][8 * g]);
            bf16x8 kb1 = *reinterpret_cast<const bf16x8*>(&K_lds[16 * nt + li][32 + 8 * g]);
            f32x4 a = {0.f, 0.f, 0.f, 0.f};
            a = MFMA(qa0, kb0, a);
            a = MFMA(qa1, kb1, a);
            s_acc[nt] = a;
        }
        // ---- QD (own rows) & KD (K-group 3-w) sharing DE frags ----
        {
            int kr = 16 * (3 - w) + li;
            bf16x8 ka0 = *reinterpret_cast<const bf16x8*>(&K_lds[kr][8 * g]);
            bf16x8 ka1 = *reinterpret_cast<const bf16x8*>(&K_lds[kr][32 + 8 * g]);
            for (int jt = 0; jt < 5; ++jt) {
                int dr = (de0 + 16 * w + 16 * jt + li) & 127;
                bf16x8 d0 = *reinterpret_cast<const bf16x8*>(&DE_lds[dr][8 * g]);
                bf16x8 d1 = *reinterpret_cast<const bf16x8*>(&DE_lds[dr][32 + 8 * g]);
                f32x4 aq = {0.f, 0.f, 0.f, 0.f};
                aq = MFMA(qa0, d0, aq);
                aq = MFMA(qa1, d1, aq);
                f32x4 ak = {0.f, 0.f, 0.f, 0.f};
                ak = MFMA(ka0, d0, ak);
                ak = MFMA(ka1, d1, ak);
                ushort4 uq;
                uq.x = f2bu(aq[0]); uq.y = f2bu(aq[1]); uq.z = f2bu(aq[2]); uq.w = f2bu(aq[3]);
                *reinterpret_cast<ushort4*>(&QD_T[w][16 * jt + li][4 * g]) = uq;
                ushort4 uk;
                uk.x = f2bu(ak[0]); uk.y = f2bu(ak[1]); uk.z = f2bu(ak[2]); uk.w = f2bu(ak[3]);
                *reinterpret_cast<ushort4*>(&KD_T[16 * jt + li][16 * (3 - w) + 4 * g]) = uk;
            }
        }
        __builtin_amdgcn_s_setprio(0);
        __syncthreads();   // QD/KD visible cross-wave; K/DE/VT[next] safe to overwrite below

        // ---- Phase C: gather (static-offset u16 reads off precomputed bases) ----
        float qdv[4][4], kdv[4][4];
        for (int nt = 0; nt < 4; ++nt)
            for (int r = 0; r < 4; ++r) {
                qdv[nt][r] = __bfloat162float(*(const __hip_bfloat16*)(qdb + 42 * r + 640 * (3 - nt)));
                kdv[nt][r] = __bfloat162float(*(const __hip_bfloat16*)(kdb + 136 * r + 32 * nt));
            }

        float pr[4][4];
        float tm[4] = {-1e30f, -1e30f, -1e30f, -1e30f};
        for (int nt = 0; nt < 4; ++nt) {
            float mk = maskb[r0 + 16 * nt + li];
            for (int r = 0; r < 4; ++r) {
                float sv = (s_acc[nt][r] + qdv[nt][r] + kdv[nt][r]) * 0.125f + mk;
                pr[nt][r] = sv;
                tm[r] = fmaxf(tm[r], sv);
            }
        }
        for (int r = 0; r < 4; ++r) tm[r] = red16max(tm[r]);
        int skip = (tm[0] <= m_run[0]) & (tm[1] <= m_run[1]) &
                   (tm[2] <= m_run[2]) & (tm[3] <= m_run[3]);
        bool all_skip = __all(skip);
        for (int r = 0; r < 4; ++r) {
            float mnew, scl;
            if (all_skip) { mnew = m_run[r]; }
            else {
                mnew = fmaxf(m_run[r], tm[r]);
                scl = exp2f((m_run[r] - mnew) * 1.44269504f);
                m_run[r] = mnew;
            }
            float ssum = 0.f;
            for (int nt = 0; nt < 4; ++nt) {
                float pv = exp2f((pr[nt][r] - mnew) * 1.44269504f);
                pr[nt][r] = pv;
                ssum += pv;
            }
            ssum = red16sum(ssum);
            if (all_skip) l_run[r] += ssum;
            else {
                l_run[r] = l_run[r] * scl + ssum;
                for (int dt = 0; dt < 4; dt++) acc_o[dt][r] *= scl;
            }
        }

        // ---- P -> wave-private LDS -> A-frags; PV MFMA (VT buf kt&1) ----
        for (int nt = 0; nt < 4; nt++)
            for (int r = 0; r < 4; r++)
                P_lds[w][4 * g + r][16 * nt + li] = __float2bfloat16(pr[nt][r]);
        bf16x8 pa0 = *reinterpret_cast<const bf16x8*>(&P_lds[w][li][8 * g]);
        bf16x8 pa1 = *reinterpret_cast<const bf16x8*>(&P_lds[w][li][32 + 8 * g]);
        __builtin_amdgcn_s_setprio(1);
        for (int dt = 0; dt < 4; dt++) {
            bf16x8 vb0 = *reinterpret_cast<const bf16x8*>(&VT_lds[kt & 1][16 * dt + li][8 * g]);
            bf16x8 vb1 = *reinterpret_cast<const bf16x8*>(&VT_lds[kt & 1][16 * dt + li][32 + 8 * g]);
            acc_o[dt] = MFMA(pa0, vb0, acc_o[dt]);
            acc_o[dt] = MFMA(pa1, vb1, acc_o[dt]);
        }
        __builtin_amdgcn_s_setprio(0);

        // ---- A': write staged regs for kt+1 (runs concurrent with other waves' C) ----
        if (has_next) {
            int dlo = de0 - 64;
            *reinterpret_cast<bf16x8*>(&K_lds[srow][scol]) = sK0;
            *reinterpret_cast<bf16x8*>(&K_lds[srow + 32][scol]) = sK1;
            *reinterpret_cast<bf16x8*>(&VT_lds[(kt + 1) & 1][srow][scol]) = sV0;
            *reinterpret_cast<bf16x8*>(&VT_lds[(kt + 1) & 1][srow + 32][scol]) = sV1;
            *reinterpret_cast<bf16x8*>(&DE_lds[(dlo + srow) & 127][scol]) = sD0;
            *reinterpret_cast<bf16x8*>(&DE_lds[(dlo + srow + 32) & 127][scol]) = sD1;
        }
        __syncthreads();   // staged tiles ready; QD/KD/P free for next Phase B
    }

    // ---- epilogue ----
    int h = bh & 15;
    for (int dt = 0; dt < 4; dt++)
        for (int r = 0; r < 4; r++) {
            int srow_ = L0 + 16 * w + 4 * g + r;
            out[((size_t)b * 1024 + srow_) * 1024 + (size_t)h * 64 + 16 * dt + li] =
                acc_o[dt][r] / l_run[r];
        }
}

// ---------------------------------------------------------------------------
extern "C" void kernel_launch(void* const* d_in, const int* in_sizes, int n_in,
                              void* d_out, int out_size, void* d_ws, size_t ws_size,
                              hipStream_t stream) {
    const float* X   = (const float*)d_in[0];
    const float* msk = (const float*)d_in[1];
    const float* Wq  = (const float*)d_in[2];
    const float* bq  = (const float*)d_in[3];
    const float* Wk  = (const float*)d_in[4];
    const float* bk  = (const float*)d_in[5];
    const float* Wv  = (const float*)d_in[6];
    const float* bv  = (const float*)d_in[7];
    const float* DE  = (const float*)d_in[8];
    float* out = (float*)d_out;

    bf16* ws  = (bf16*)d_ws;
    bf16* Xb  = ws;              // 4194304
    bf16* WTb = ws + 4194304;    // 3145728
    bf16* DEb = ws + 7340032;    // 262144
    bf16* Qb  = ws + 7602176;    // 4194304
    bf16* Kb  = ws + 11796480;   // 4194304
    bf16* VTb = ws + 15990784;   // 4194304

    prep_convert<<<4352, 256, 0, stream>>>(X, DE, Xb, DEb);
    prep_transpose_w<<<dim3(16, 16, 3), 256, 0, stream>>>(Wq, Wk, Wv, WTb);
    proj_gemm<<<dim3(32, 8, 3), 256, 0, stream>>>(Xb, WTb, bq, bk, bv, Qb, Kb, VTb);
    attn_fused<<<dim3(1024), 256, 0, stream>>>(Qb, Kb, VTb, DEb, msk, out);
}